// Round 3
// baseline (606.111 us; speedup 1.0000x reference)
//
#include <hip/hip_runtime.h>

#define L 2048
#define D 1024
#define H 16
#define Z 64
#define HZ 1024

typedef __bf16 bf16x8 __attribute__((ext_vector_type(8)));
typedef float f32x4 __attribute__((ext_vector_type(4)));
typedef float f32x16 __attribute__((ext_vector_type(16)));

// ---------------------------------------------------------------------------
// 64-row x 128-byte tile staging into fragment-friendly regions (for 16x16 path)
// ---------------------------------------------------------------------------
__device__ __forceinline__ void stage64(const __bf16* __restrict__ g, int gstride,
                                        char* lds, int tid) {
  const int lane = tid & 63, w = tid >> 6;
#pragma unroll
  for (int it = 0; it < 2; ++it) {
    const int region = it * 4 + w;
    const int r = ((region >> 1) << 4) + (lane & 15);
    const int c = ((region & 1) << 2) + (lane >> 4);
    const uint4 v = *(const uint4*)(g + (size_t)r * gstride + c * 8);
    *(uint4*)(lds + (region << 10) + (lane << 4)) = v;
  }
}

__device__ __forceinline__ bf16x8 frag(const char* lds, int blk, int t, int lane) {
  return *(const bf16x8*)(lds + (((blk << 1) + t) << 10) + (lane << 4));
}

// ---------------------------------------------------------------------------
// grad-kernel tile staging: 64 rows x 64 bf16; region=(row>>4)*2+(cc>>2),
// slot=(row&15)+(cc&3)*16  (cc = 16B chunk 0..7). Conflict-free frag reads.
// ---------------------------------------------------------------------------
__device__ __forceinline__ void stage_tile(const __bf16* __restrict__ g,
                                           int rowstride, char* lds, int tid) {
#pragma unroll
  for (int it = 0; it < 2; ++it) {
    const int p = tid + it * 256;           // 0..511 pieces
    const int r = p >> 3, cc = p & 7;
    const int region = ((r >> 4) << 1) + (cc >> 2);
    const int slot = (r & 15) + ((cc & 3) << 4);
    *(uint4*)(lds + region * 1024 + slot * 16) =
        *(const uint4*)(g + (size_t)r * rowstride + cc * 8);
  }
}

__device__ __forceinline__ bf16x8 rfrag(const char* lds, int row, int cc) {
  const int region = ((row >> 4) << 1) + (cc >> 2);
  const int slot = (row & 15) + ((cc & 3) << 4);
  return *(const bf16x8*)(lds + region * 1024 + slot * 16);
}

// ---------------------------------------------------------------------------
// fp32 -> bf16 flat convert (n4 = n/4)
// ---------------------------------------------------------------------------
__global__ __launch_bounds__(256) void cvt_kernel(const float* __restrict__ s,
                                                  __bf16* __restrict__ d, int n4) {
  int i = blockIdx.x * 256 + threadIdx.x;
  if (i < n4) {
    float4 v = ((const float4*)s)[i];
    union { __bf16 h[4]; uint2 u; } o;
    o.h[0] = (__bf16)v.x; o.h[1] = (__bf16)v.y;
    o.h[2] = (__bf16)v.z; o.h[3] = (__bf16)v.w;
    ((uint2*)d)[i] = o.u;
  }
}

// ---------------------------------------------------------------------------
// Wt[d][hz] = (bf16)W[hz][d]   (1024x1024 transpose, 64x64 tiles) - for gx
// ---------------------------------------------------------------------------
__global__ __launch_bounds__(256) void wt_kernel(const float* __restrict__ Wk,
                                                 const float* __restrict__ Wq,
                                                 __bf16* __restrict__ Wkt,
                                                 __bf16* __restrict__ Wqt) {
  const float* W = blockIdx.z ? Wq : Wk;
  __bf16* Wt = blockIdx.z ? Wqt : Wkt;
  __shared__ __bf16 tile[64][65];
  const int r0 = blockIdx.y * 64, c0 = blockIdx.x * 64;
  const int c = threadIdx.x & 63, rb = threadIdx.x >> 6;
#pragma unroll
  for (int i = 0; i < 16; ++i) {
    int r = rb + i * 4;
    tile[r][c] = (__bf16)W[(size_t)(r0 + r) * D + c0 + c];
  }
  __syncthreads();
#pragma unroll
  for (int i = 0; i < 16; ++i) {
    int r = rb + i * 4;
    Wt[(size_t)(c0 + r) * HZ + r0 + c] = tile[c][r];
  }
}

// ---------------------------------------------------------------------------
// proj: kp/qp[bh][l][z] = sum_d x*W ; kpt/qpt[bh][z][l] in PERMUTED l-order:
// within each 16-l group, 4-el pieces stored in order [l0-3, l8-11, l4-7, l12-15]
// so grad PV B-fragments become contiguous 16B reads.
// ---------------------------------------------------------------------------
__global__ __launch_bounds__(256) void proj_kernel(
    const __bf16* __restrict__ xb, const __bf16* __restrict__ Wkb,
    const __bf16* __restrict__ Wqb,
    __bf16* __restrict__ kp, __bf16* __restrict__ qp,
    __bf16* __restrict__ kpt, __bf16* __restrict__ qpt) {
  const __bf16* __restrict__ Wb = blockIdx.z ? Wqb : Wkb;
  __bf16* __restrict__ outn = blockIdx.z ? qp : kp;
  __bf16* __restrict__ outt = blockIdx.z ? qpt : kpt;
  const int h = blockIdx.x, m0 = blockIdx.y * 64;
  const int tid = threadIdx.x, lane = tid & 63, w = tid >> 6;
  const int tx = lane & 15, quad = lane >> 4;
  __shared__ __align__(16) char sA[8192], sB[8192];
  f32x4 acc[4];
#pragma unroll
  for (int nb = 0; nb < 4; ++nb)
#pragma unroll
    for (int i = 0; i < 4; ++i) acc[nb][i] = 0.f;
  for (int k0 = 0; k0 < D; k0 += 64) {
    __syncthreads();
    stage64(xb + (size_t)m0 * D + k0, D, sA, tid);
    stage64(Wb + (size_t)h * 64 * D + k0, D, sB, tid);
    __syncthreads();
#pragma unroll
    for (int t = 0; t < 2; ++t) {
      bf16x8 a = frag(sA, w, t, lane);
#pragma unroll
      for (int nb = 0; nb < 4; ++nb)
        acc[nb] = __builtin_amdgcn_mfma_f32_16x16x32_bf16(
            a, frag(sB, nb, t, lane), acc[nb], 0, 0, 0);
    }
  }
  const size_t bh = (size_t)(m0 >> 11) * H + h;
  const int l0 = (m0 & (L - 1)) + 16 * w + 4 * quad;
  const int l0p = (m0 & (L - 1)) + 16 * w + ((quad & 1) << 3) + ((quad >> 1) << 2);
#pragma unroll
  for (int nb = 0; nb < 4; ++nb) {
    const int z = nb * 16 + tx;
    union { __bf16 hh[4]; uint2 u; } pk;
#pragma unroll
    for (int r = 0; r < 4; ++r) pk.hh[r] = (__bf16)acc[nb][r];
    *(uint2*)(outt + (bh * Z + z) * L + l0p) = pk.u;
#pragma unroll
    for (int r = 0; r < 4; ++r) outn[(bh * L + l0 + r) * Z + z] = pk.hh[r];
  }
}

// ---------------------------------------------------------------------------
// grad kernel (32x32x16 MFMA, register-resident B, in-register P transform).
// MODE 0: Gkp[q][z] = -(1/li_q) sum_c exp(b*S[q][c]) * qp[c][z]; lse=log(li)
// MODE 1: Gqp[kq][z] = -sum_q exp(b*S[q][kq]) * kpw[q][z]   (kpw pre-scaled)
// Rg: resident rows [bh][l][z]; Sg: streamed rows [bh][l][z];
// Tg: PV B operand [bh][z][L] (l-permuted). grid (16 qt, 32 bh), 256 thr.
// ---------------------------------------------------------------------------
template<int MODE>
__global__ __launch_bounds__(256, 2) void grad_kernel(
    const __bf16* __restrict__ Rg, const __bf16* __restrict__ Sg,
    const __bf16* __restrict__ Tg, const float* __restrict__ beta_p,
    float* __restrict__ lse, __bf16* __restrict__ Gout) {
  const int qt = blockIdx.x, bh = blockIdx.y;
  const float beta = beta_p[0];
  const int tid = threadIdx.x, l = tid & 63, w = tid >> 6;
  const int l31 = l & 31, hi = l >> 5;
  const int s = w >> 1, h = w & 1;      // strip, c-half
  const int q0 = qt * 128 + s * 64;
  __shared__ __align__(16) char sS[8192], sT[8192];
  __shared__ float red[2][64][66];
  __shared__ float lil[2][2][64];

  // resident operand as 32x32x16 B-fragments (n = q = l31, k = z = ks*16+hi*8+j)
  bf16x8 bres[2][4];
#pragma unroll
  for (int nt = 0; nt < 2; ++nt)
#pragma unroll
    for (int ks = 0; ks < 4; ++ks)
      bres[nt][ks] = *(const bf16x8*)(
          Rg + ((size_t)bh * L + q0 + nt * 32 + l31) * Z + ks * 16 + hi * 8);

  f32x16 pv[2][2];
#pragma unroll
  for (int a = 0; a < 2; ++a)
#pragma unroll
    for (int b = 0; b < 2; ++b)
#pragma unroll
      for (int i = 0; i < 16; ++i) pv[a][b][i] = 0.f;
  float li[2] = {0.f, 0.f};

  for (int kt = 0; kt < 32; ++kt) {
    __syncthreads();
    stage_tile(Sg + ((size_t)bh * L + kt * 64) * Z, Z, sS, tid);
    stage_tile(Tg + (size_t)bh * Z * L + kt * 64, L, sT, tid);
    __syncthreads();
    // St[c][q] = sum_z streamed[c][z] * resident[q][z]  (A = streamed, B = resident)
    f32x16 st[2];
#pragma unroll
    for (int i = 0; i < 16; ++i) { st[0][i] = 0.f; st[1][i] = 0.f; }
#pragma unroll
    for (int ks = 0; ks < 4; ++ks) {
      bf16x8 a = rfrag(sS, 32 * h + l31, 2 * ks + hi);
      st[0] = __builtin_amdgcn_mfma_f32_32x32x16_bf16(a, bres[0][ks], st[0], 0, 0, 0);
      st[1] = __builtin_amdgcn_mfma_f32_32x32x16_bf16(a, bres[1][ks], st[1], 0, 0, 0);
    }
    // P = exp(beta*St) (fixed max = 0), packed straight into PV A-fragments
    uint32_t P32[2][8];
#pragma unroll
    for (int nt = 0; nt < 2; ++nt) {
      float lsn = 0.f;
#pragma unroll
      for (int i = 0; i < 8; ++i) {
        float e0 = __expf(beta * st[nt][2 * i]);
        float e1 = __expf(beta * st[nt][2 * i + 1]);
        if (MODE == 0) lsn += e0 + e1;
        union { __bf16 hh[2]; uint32_t u; } pk;
        pk.hh[0] = (__bf16)e0; pk.hh[1] = (__bf16)e1;
        P32[nt][i] = pk.u;
      }
      if (MODE == 0) li[nt] += lsn + __shfl_xor(lsn, 32);
    }
    // PV: D[q][z] += P[q][c] * T[c][z]; A from regs, B from permuted sT
#pragma unroll
    for (int kp2 = 0; kp2 < 2; ++kp2) {
      union { uint32_t u[4]; bf16x8 v; } a0, a1;
#pragma unroll
      for (int i = 0; i < 4; ++i) {
        a0.u[i] = P32[0][4 * kp2 + i];
        a1.u[i] = P32[1][4 * kp2 + i];
      }
#pragma unroll
      for (int zt = 0; zt < 2; ++zt) {
        bf16x8 bb = rfrag(sT, 32 * zt + l31, 4 * h + 2 * kp2 + hi);
        pv[0][zt] = __builtin_amdgcn_mfma_f32_32x32x16_bf16(a0.v, bb, pv[0][zt], 0, 0, 0);
        pv[1][zt] = __builtin_amdgcn_mfma_f32_32x32x16_bf16(a1.v, bb, pv[1][zt], 0, 0, 0);
      }
    }
  }
  // cross-wave (c-half) reduction: each wave posts its partner z-half + li
#pragma unroll
  for (int nt = 0; nt < 2; ++nt)
#pragma unroll
    for (int r = 0; r < 16; ++r) {
      int qrow = nt * 32 + (r & 3) + ((r >> 2) << 3) + (hi << 2);
      red[s][qrow][(1 - h) * 32 + l31] = pv[nt][1 - h][r];
    }
  if (MODE == 0 && hi == 0) { lil[s][h][l31] = li[0]; lil[s][h][32 + l31] = li[1]; }
  __syncthreads();
  const int b = bh >> 4, hh = bh & (H - 1);
#pragma unroll
  for (int nt = 0; nt < 2; ++nt)
#pragma unroll
    for (int r = 0; r < 16; ++r) {
      int qrow = nt * 32 + (r & 3) + ((r >> 2) << 3) + (hi << 2);
      float v = pv[nt][h][r] + red[s][qrow][h * 32 + l31];
      if (MODE == 0) v /= (lil[s][0][qrow] + lil[s][1][qrow]);
      Gout[((size_t)b * L + q0 + qrow) * HZ + hh * Z + h * 32 + l31] = (__bf16)(-v);
    }
  if (MODE == 0 && hi == 0 && h == 0) {
#pragma unroll
    for (int nt = 0; nt < 2; ++nt) {
      float lt = lil[s][0][nt * 32 + l31] + lil[s][1][nt * 32 + l31];
      lse[(size_t)bh * L + q0 + nt * 32 + l31] = __logf(lt);
    }
  }
}

// ---------------------------------------------------------------------------
// kpt[row][pos] *= exp(-lse[true_l(pos)])  (in place; pos is l-permuted)
// ---------------------------------------------------------------------------
__global__ __launch_bounds__(256) void kscale_kernel(__bf16* __restrict__ kpt,
                                                     const float* __restrict__ lse) {
  int idx = blockIdx.x * 256 + threadIdx.x;   // 1M 4-el pieces
  int row = idx >> 9;                          // bh*64 + z
  int pos4 = (idx & 511) << 2;
  int bh = row >> 6;
  int lbase = (pos4 & ~15) + (((pos4 >> 2) & 1) << 3) + (((pos4 >> 3) & 1) << 2);
  float4 ls = *(const float4*)(lse + (size_t)bh * L + lbase);
  __bf16* p = kpt + (size_t)row * L + pos4;
  union { __bf16 hh[4]; uint2 u; } v;
  v.u = *(uint2*)p;
  v.hh[0] = (__bf16)((float)v.hh[0] * __expf(-ls.x));
  v.hh[1] = (__bf16)((float)v.hh[1] * __expf(-ls.y));
  v.hh[2] = (__bf16)((float)v.hh[2] * __expf(-ls.z));
  v.hh[3] = (__bf16)((float)v.hh[3] * __expf(-ls.w));
  *(uint2*)p = v.u;
}

// ---------------------------------------------------------------------------
// en[b] = -(1/beta) * sum_{h,q} lse[b,h,q]
// ---------------------------------------------------------------------------
__global__ __launch_bounds__(256) void energy_kernel(
    const float* __restrict__ lse_ws, const float* __restrict__ beta_p,
    float* __restrict__ out) {
  const int b = blockIdx.x;
  const float* p = lse_ws + (size_t)b * H * L;
  float sum = 0.f;
  for (int i = threadIdx.x; i < H * L; i += 256) sum += p[i];
#pragma unroll
  for (int off = 1; off < 64; off <<= 1) sum += __shfl_xor(sum, off, 64);
  __shared__ float wsum[4];
  if ((threadIdx.x & 63) == 0) wsum[threadIdx.x >> 6] = sum;
  __syncthreads();
  if (threadIdx.x == 0)
    out[b] = -(wsum[0] + wsum[1] + wsum[2] + wsum[3]) / beta_p[0];
}

// ---------------------------------------------------------------------------
// gx[m][d] = sum_hz Gkp[m][hz]*Wk[hz][d] + Gqp[m][hz]*Wq[hz][d]
// ---------------------------------------------------------------------------
__global__ __launch_bounds__(256) void gx_kernel(
    const __bf16* __restrict__ Gkp, const __bf16* __restrict__ Gqp,
    const __bf16* __restrict__ Wkt, const __bf16* __restrict__ Wqt,
    float* __restrict__ gx) {
  const int n0 = blockIdx.x * 64, m0 = blockIdx.y * 64;
  const int tid = threadIdx.x, lane = tid & 63, w = tid >> 6;
  const int tx = lane & 15, quad = lane >> 4;
  __shared__ __align__(16) char sA[8192], sB[8192];
  f32x4 acc[4];
#pragma unroll
  for (int nb = 0; nb < 4; ++nb)
#pragma unroll
    for (int i = 0; i < 4; ++i) acc[nb][i] = 0.f;
#pragma unroll 1
  for (int src = 0; src < 2; ++src) {
    const __bf16* __restrict__ A = src ? Gqp : Gkp;
    const __bf16* __restrict__ Bt = src ? Wqt : Wkt;
    for (int k0 = 0; k0 < HZ; k0 += 64) {
      __syncthreads();
      stage64(A + (size_t)m0 * HZ + k0, HZ, sA, tid);
      stage64(Bt + (size_t)n0 * HZ + k0, HZ, sB, tid);
      __syncthreads();
#pragma unroll
      for (int t = 0; t < 2; ++t) {
        bf16x8 a = frag(sA, w, t, lane);
#pragma unroll
        for (int nb = 0; nb < 4; ++nb)
          acc[nb] = __builtin_amdgcn_mfma_f32_16x16x32_bf16(
              a, frag(sB, nb, t, lane), acc[nb], 0, 0, 0);
      }
    }
  }
#pragma unroll
  for (int nb = 0; nb < 4; ++nb)
#pragma unroll
    for (int r = 0; r < 4; ++r)
      gx[(size_t)(m0 + 16 * w + 4 * quad + r) * D + n0 + nb * 16 + tx] =
          acc[nb][r];
}

// ---------------------------------------------------------------------------
extern "C" void kernel_launch(void* const* d_in, const int* in_sizes, int n_in,
                              void* d_out, int out_size, void* d_ws, size_t ws_size,
                              hipStream_t stream) {
  const float* x    = (const float*)d_in[0];
  const float* Wq   = (const float*)d_in[1];
  const float* Wk   = (const float*)d_in[2];
  const float* beta = (const float*)d_in[3];
  float* out = (float*)d_out;

  char* ws = (char*)d_ws;
  __bf16* xb  = (__bf16*)(ws);                         // 8 MB
  __bf16* Wkb = (__bf16*)(ws + (8ull  << 20));         // 2 MB
  __bf16* Wqb = (__bf16*)(ws + (10ull << 20));         // 2 MB
  __bf16* Wkt = (__bf16*)(ws + (12ull << 20));         // 2 MB
  __bf16* Wqt = (__bf16*)(ws + (14ull << 20));         // 2 MB
  __bf16* kp  = (__bf16*)(ws + (16ull << 20));         // 8 MB
  __bf16* qp  = (__bf16*)(ws + (24ull << 20));         // 8 MB
  __bf16* kpt = (__bf16*)(ws + (32ull << 20));         // 8 MB (l-permuted)
  __bf16* qpt = (__bf16*)(ws + (40ull << 20));         // 8 MB (l-permuted)
  __bf16* Gkp = (__bf16*)(ws + (48ull << 20));         // 8 MB
  __bf16* Gqp = (__bf16*)(ws + (56ull << 20));         // 8 MB
  float*  lse = (float*)(ws + (64ull << 20));          // 256 KB

  cvt_kernel<<<4096, 256, 0, stream>>>(x, xb, 1048576);
  cvt_kernel<<<1024, 256, 0, stream>>>(Wk, Wkb, 262144);
  cvt_kernel<<<1024, 256, 0, stream>>>(Wq, Wqb, 262144);
  wt_kernel<<<dim3(16, 16, 2), 256, 0, stream>>>(Wk, Wq, Wkt, Wqt);
  proj_kernel<<<dim3(16, 64, 2), 256, 0, stream>>>(xb, Wkb, Wqb, kp, qp, kpt, qpt);
  grad_kernel<0><<<dim3(16, 32), 256, 0, stream>>>(kp, qp, qpt, beta, lse, Gkp);
  kscale_kernel<<<4096, 256, 0, stream>>>(kpt, lse);
  grad_kernel<1><<<dim3(16, 32), 256, 0, stream>>>(qp, kp, kpt, beta, lse, Gqp);
  energy_kernel<<<2, 256, 0, stream>>>(lse, beta, out);
  gx_kernel<<<dim3(16, 64), 256, 0, stream>>>(Gkp, Gqp, Wkt, Wqt, out + 2);
}

// Round 4
// 410.488 us; speedup vs baseline: 1.4766x; 1.4766x over previous
//
#include <hip/hip_runtime.h>

#define L 2048
#define D 1024
#define H 16
#define Z 64
#define HZ 1024

typedef __bf16 bf16x8 __attribute__((ext_vector_type(8)));
typedef float f32x4 __attribute__((ext_vector_type(4)));
typedef float f32x16 __attribute__((ext_vector_type(16)));

// ---------------------------------------------------------------------------
// 64-row x 128-byte tile staging, linear lane*16B writes (conflict-free).
//   region = it*4 + wave; row = (region>>1)*16 + (lane&15);
//   col8   = (region&1)*4 + (lane>>4)   (8-element chunks)
// ---------------------------------------------------------------------------
__device__ __forceinline__ void stage64(const __bf16* __restrict__ g, int gstride,
                                        char* lds, int tid) {
  const int lane = tid & 63, w = tid >> 6;
#pragma unroll
  for (int it = 0; it < 2; ++it) {
    const int region = it * 4 + w;
    const int r = ((region >> 1) << 4) + (lane & 15);
    const int c = ((region & 1) << 2) + (lane >> 4);
    const uint4 v = *(const uint4*)(g + (size_t)r * gstride + c * 8);
    *(uint4*)(lds + (region << 10) + (lane << 4)) = v;
  }
}

// 16x16-path fragment read (linear)
__device__ __forceinline__ bf16x8 frag(const char* lds, int blk, int t, int lane) {
  return *(const bf16x8*)(lds + (((blk << 1) + t) << 10) + (lane << 4));
}

// (row, col8) fragment read, inverse of stage64's mapping
__device__ __forceinline__ bf16x8 rfrag(const char* lds, int row, int cc) {
  const int region = ((row >> 4) << 1) + (cc >> 2);
  const int slot = (row & 15) + ((cc & 3) << 4);
  return *(const bf16x8*)(lds + region * 1024 + slot * 16);
}

// ---------------------------------------------------------------------------
// fp32 -> bf16 flat convert (n4 = n/4)
// ---------------------------------------------------------------------------
__global__ __launch_bounds__(256) void cvt_kernel(const float* __restrict__ s,
                                                  __bf16* __restrict__ d, int n4) {
  int i = blockIdx.x * 256 + threadIdx.x;
  if (i < n4) {
    float4 v = ((const float4*)s)[i];
    union { __bf16 h[4]; uint2 u; } o;
    o.h[0] = (__bf16)v.x; o.h[1] = (__bf16)v.y;
    o.h[2] = (__bf16)v.z; o.h[3] = (__bf16)v.w;
    ((uint2*)d)[i] = o.u;
  }
}

// ---------------------------------------------------------------------------
// Wt[d][hz] = (bf16)W[hz][d]   (1024x1024 transpose, 64x64 tiles) - for gx
// ---------------------------------------------------------------------------
__global__ __launch_bounds__(256) void wt_kernel(const float* __restrict__ Wk,
                                                 const float* __restrict__ Wq,
                                                 __bf16* __restrict__ Wkt,
                                                 __bf16* __restrict__ Wqt) {
  const float* W = blockIdx.z ? Wq : Wk;
  __bf16* Wt = blockIdx.z ? Wqt : Wkt;
  __shared__ __bf16 tile[64][65];
  const int r0 = blockIdx.y * 64, c0 = blockIdx.x * 64;
  const int c = threadIdx.x & 63, rb = threadIdx.x >> 6;
#pragma unroll
  for (int i = 0; i < 16; ++i) {
    int r = rb + i * 4;
    tile[r][c] = (__bf16)W[(size_t)(r0 + r) * D + c0 + c];
  }
  __syncthreads();
#pragma unroll
  for (int i = 0; i < 16; ++i) {
    int r = rb + i * 4;
    Wt[(size_t)(c0 + r) * HZ + r0 + c] = tile[c][r];
  }
}

// ---------------------------------------------------------------------------
// proj: kp/qp[bh][l][z] = sum_d x*W ; kpt/qpt[bh][z][l] in PERMUTED l-order:
// within each 16-l group, 4-el pieces stored in order [l0-3, l8-11, l4-7, l12-15]
// so grad PV B-fragments become contiguous 16B reads.
// ---------------------------------------------------------------------------
__global__ __launch_bounds__(256) void proj_kernel(
    const __bf16* __restrict__ xb, const __bf16* __restrict__ Wkb,
    const __bf16* __restrict__ Wqb,
    __bf16* __restrict__ kp, __bf16* __restrict__ qp,
    __bf16* __restrict__ kpt, __bf16* __restrict__ qpt) {
  const __bf16* __restrict__ Wb = blockIdx.z ? Wqb : Wkb;
  __bf16* __restrict__ outn = blockIdx.z ? qp : kp;
  __bf16* __restrict__ outt = blockIdx.z ? qpt : kpt;
  const int h = blockIdx.x, m0 = blockIdx.y * 64;
  const int tid = threadIdx.x, lane = tid & 63, w = tid >> 6;
  const int tx = lane & 15, quad = lane >> 4;
  __shared__ __align__(16) char sA[8192], sB[8192];
  f32x4 acc[4];
#pragma unroll
  for (int nb = 0; nb < 4; ++nb)
#pragma unroll
    for (int i = 0; i < 4; ++i) acc[nb][i] = 0.f;
  for (int k0 = 0; k0 < D; k0 += 64) {
    __syncthreads();
    stage64(xb + (size_t)m0 * D + k0, D, sA, tid);
    stage64(Wb + (size_t)h * 64 * D + k0, D, sB, tid);
    __syncthreads();
#pragma unroll
    for (int t = 0; t < 2; ++t) {
      bf16x8 a = frag(sA, w, t, lane);
#pragma unroll
      for (int nb = 0; nb < 4; ++nb)
        acc[nb] = __builtin_amdgcn_mfma_f32_16x16x32_bf16(
            a, frag(sB, nb, t, lane), acc[nb], 0, 0, 0);
    }
  }
  const size_t bh = (size_t)(m0 >> 11) * H + h;
  const int l0 = (m0 & (L - 1)) + 16 * w + 4 * quad;
  const int l0p = (m0 & (L - 1)) + 16 * w + ((quad & 1) << 3) + ((quad >> 1) << 2);
#pragma unroll
  for (int nb = 0; nb < 4; ++nb) {
    const int z = nb * 16 + tx;
    union { __bf16 hh[4]; uint2 u; } pk;
#pragma unroll
    for (int r = 0; r < 4; ++r) pk.hh[r] = (__bf16)acc[nb][r];
    *(uint2*)(outt + (bh * Z + z) * L + l0p) = pk.u;
#pragma unroll
    for (int r = 0; r < 4; ++r) outn[(bh * L + l0 + r) * Z + z] = pk.hh[r];
  }
}

// ---------------------------------------------------------------------------
// grad kernel: 32x32x16 MFMA, 1 q-tile (32 rows) per wave, full c=64, z=64.
// MODE 0: Gkp[q][z] = -(1/li_q) sum_c exp(b*S[q][c]) * qp[c][z]; lse=log(li)
// MODE 1: Gqp[kq][z] = -sum_q exp(b*S[q][kq]) * kpw[q][z]  (kpw pre-scaled)
// Rg: resident rows [bh][l][z] (reg-held B-frags); Sg: streamed rows [bh][l][z]
// (A-frags loaded DIRECTLY from global, L1-shared across waves);
// Tg: PV B operand [bh][z][L], l-permuted, staged via LDS.
// grid = 512 blocks, XCD-swizzled so each XCD works on 4 bh.
// ---------------------------------------------------------------------------
template<int MODE>
__global__ __launch_bounds__(256, 2) void grad_kernel(
    const __bf16* __restrict__ Rg, const __bf16* __restrict__ Sg,
    const __bf16* __restrict__ Tg, const float* __restrict__ beta_p,
    float* __restrict__ lse, __bf16* __restrict__ Gout) {
  const int bid = blockIdx.x;
  const int slot = bid >> 3;
  const int bh = (bid & 7) * 4 + (slot >> 4);   // 4 bh per XCD
  const int qt = slot & 15;
  const float beta = beta_p[0];
  const int tid = threadIdx.x, l = tid & 63, w = tid >> 6;
  const int l31 = l & 31, hi = l >> 5;
  const int q0 = qt * 128 + w * 32;             // this wave's 32 resident rows
  __shared__ __align__(16) char sT[8192];

  // resident operand as 32x32x16 B-fragments: B[n=l31][k=16ks+8hi+j]
  bf16x8 bres[4];
#pragma unroll
  for (int ks = 0; ks < 4; ++ks)
    bres[ks] = *(const bf16x8*)(
        Rg + ((size_t)bh * L + q0 + l31) * Z + ks * 16 + hi * 8);

  f32x16 pv[2];
#pragma unroll
  for (int zt = 0; zt < 2; ++zt)
#pragma unroll
    for (int i = 0; i < 16; ++i) pv[zt][i] = 0.f;
  float li = 0.f;

  const __bf16* __restrict__ Sbase =
      Sg + (size_t)bh * L * Z + (size_t)l31 * Z + hi * 8;
  const __bf16* __restrict__ Tbase = Tg + (size_t)bh * Z * L;

  for (int kt = 0; kt < 32; ++kt) {
    // A-fragments for St direct from global (each wave reads whole tile; L1 reuse)
    bf16x8 av[2][4];
#pragma unroll
    for (int nt = 0; nt < 2; ++nt)
#pragma unroll
      for (int ks = 0; ks < 4; ++ks)
        av[nt][ks] = *(const bf16x8*)(
            Sbase + (size_t)(kt * 64 + nt * 32) * Z + ks * 16);
    __syncthreads();
    stage64(Tbase + kt * 64, L, sT, tid);
    __syncthreads();
    // St[c][q] = sum_z streamed[c][z] * resident[q][z]
    f32x16 st[2];
#pragma unroll
    for (int i = 0; i < 16; ++i) { st[0][i] = 0.f; st[1][i] = 0.f; }
#pragma unroll
    for (int ks = 0; ks < 4; ++ks) {
      st[0] = __builtin_amdgcn_mfma_f32_32x32x16_bf16(av[0][ks], bres[ks], st[0], 0, 0, 0);
      st[1] = __builtin_amdgcn_mfma_f32_32x32x16_bf16(av[1][ks], bres[ks], st[1], 0, 0, 0);
    }
    // P = exp(beta*St) (fixed max=0; |beta*S| small), packed as PV A-frags
    uint32_t P32[2][8];
    float lsn = 0.f;
#pragma unroll
    for (int nt = 0; nt < 2; ++nt)
#pragma unroll
      for (int i = 0; i < 8; ++i) {
        float e0 = __expf(beta * st[nt][2 * i]);
        float e1 = __expf(beta * st[nt][2 * i + 1]);
        if (MODE == 0) lsn += e0 + e1;
        union { __bf16 hh[2]; uint32_t u; } pk;
        pk.hh[0] = (__bf16)e0; pk.hh[1] = (__bf16)e1;
        P32[nt][i] = pk.u;
      }
    if (MODE == 0) li += lsn;
    // PV: D[q][z] += P[q][c] * T[c][z]
#pragma unroll
    for (int kc = 0; kc < 4; ++kc) {
      union { uint32_t u[4]; bf16x8 v; } a;
#pragma unroll
      for (int i = 0; i < 4; ++i) a.u[i] = P32[kc >> 1][4 * (kc & 1) + i];
      pv[0] = __builtin_amdgcn_mfma_f32_32x32x16_bf16(
          a.v, rfrag(sT, l31, 2 * kc + hi), pv[0], 0, 0, 0);
      pv[1] = __builtin_amdgcn_mfma_f32_32x32x16_bf16(
          a.v, rfrag(sT, 32 + l31, 2 * kc + hi), pv[1], 0, 0, 0);
    }
  }
  if (MODE == 0) li += __shfl_xor(li, 32);   // partner holds the other 32 c's
  const int b = bh >> 4, head = bh & (H - 1);
#pragma unroll
  for (int r = 0; r < 16; ++r) {
    const int qoff = (r & 3) + 8 * (r >> 2) + 4 * hi;   // C-layout row
    float scl = 1.f;
    if (MODE == 0)
      scl = 1.f / __int_as_float(
                __builtin_amdgcn_ds_bpermute(4 * qoff, __float_as_int(li)));
    const size_t orow = ((size_t)b * L + q0 + qoff) * HZ + head * Z;
    Gout[orow + l31]      = (__bf16)(-pv[0][r] * scl);
    Gout[orow + 32 + l31] = (__bf16)(-pv[1][r] * scl);
  }
  if (MODE == 0 && hi == 0)
    lse[(size_t)bh * L + q0 + l31] = __logf(li);
}

// ---------------------------------------------------------------------------
// kpt[row][pos] *= exp(-lse[true_l(pos)])  (in place; pos is l-permuted)
// ---------------------------------------------------------------------------
__global__ __launch_bounds__(256) void kscale_kernel(__bf16* __restrict__ kpt,
                                                     const float* __restrict__ lse) {
  int idx = blockIdx.x * 256 + threadIdx.x;   // 1M 4-el pieces
  int row = idx >> 9;                          // bh*64 + z
  int pos4 = (idx & 511) << 2;
  int bh = row >> 6;
  int lbase = (pos4 & ~15) + (((pos4 >> 2) & 1) << 3) + (((pos4 >> 3) & 1) << 2);
  float4 ls = *(const float4*)(lse + (size_t)bh * L + lbase);
  __bf16* p = kpt + (size_t)row * L + pos4;
  union { __bf16 hh[4]; uint2 u; } v;
  v.u = *(uint2*)p;
  v.hh[0] = (__bf16)((float)v.hh[0] * __expf(-ls.x));
  v.hh[1] = (__bf16)((float)v.hh[1] * __expf(-ls.y));
  v.hh[2] = (__bf16)((float)v.hh[2] * __expf(-ls.z));
  v.hh[3] = (__bf16)((float)v.hh[3] * __expf(-ls.w));
  *(uint2*)p = v.u;
}

// ---------------------------------------------------------------------------
// en[b] = -(1/beta) * sum_{h,q} lse[b,h,q]
// ---------------------------------------------------------------------------
__global__ __launch_bounds__(256) void energy_kernel(
    const float* __restrict__ lse_ws, const float* __restrict__ beta_p,
    float* __restrict__ out) {
  const int b = blockIdx.x;
  const float* p = lse_ws + (size_t)b * H * L;
  float sum = 0.f;
  for (int i = threadIdx.x; i < H * L; i += 256) sum += p[i];
#pragma unroll
  for (int off = 1; off < 64; off <<= 1) sum += __shfl_xor(sum, off, 64);
  __shared__ float wsum[4];
  if ((threadIdx.x & 63) == 0) wsum[threadIdx.x >> 6] = sum;
  __syncthreads();
  if (threadIdx.x == 0)
    out[b] = -(wsum[0] + wsum[1] + wsum[2] + wsum[3]) / beta_p[0];
}

// ---------------------------------------------------------------------------
// gx[m][d] = sum_hz Gkp[m][hz]*Wk[hz][d] + Gqp[m][hz]*Wq[hz][d]
// ---------------------------------------------------------------------------
__global__ __launch_bounds__(256) void gx_kernel(
    const __bf16* __restrict__ Gkp, const __bf16* __restrict__ Gqp,
    const __bf16* __restrict__ Wkt, const __bf16* __restrict__ Wqt,
    float* __restrict__ gx) {
  const int n0 = blockIdx.x * 64, m0 = blockIdx.y * 64;
  const int tid = threadIdx.x, lane = tid & 63, w = tid >> 6;
  const int tx = lane & 15, quad = lane >> 4;
  __shared__ __align__(16) char sA[8192], sB[8192];
  f32x4 acc[4];
#pragma unroll
  for (int nb = 0; nb < 4; ++nb)
#pragma unroll
    for (int i = 0; i < 4; ++i) acc[nb][i] = 0.f;
#pragma unroll 1
  for (int src = 0; src < 2; ++src) {
    const __bf16* __restrict__ A = src ? Gqp : Gkp;
    const __bf16* __restrict__ Bt = src ? Wqt : Wkt;
    for (int k0 = 0; k0 < HZ; k0 += 64) {
      __syncthreads();
      stage64(A + (size_t)m0 * HZ + k0, HZ, sA, tid);
      stage64(Bt + (size_t)n0 * HZ + k0, HZ, sB, tid);
      __syncthreads();
#pragma unroll
      for (int t = 0; t < 2; ++t) {
        bf16x8 a = frag(sA, w, t, lane);
#pragma unroll
        for (int nb = 0; nb < 4; ++nb)
          acc[nb] = __builtin_amdgcn_mfma_f32_16x16x32_bf16(
              a, frag(sB, nb, t, lane), acc[nb], 0, 0, 0);
      }
    }
  }
#pragma unroll
  for (int nb = 0; nb < 4; ++nb)
#pragma unroll
    for (int r = 0; r < 4; ++r)
      gx[(size_t)(m0 + 16 * w + 4 * quad + r) * D + n0 + nb * 16 + tx] =
          acc[nb][r];
}

// ---------------------------------------------------------------------------
extern "C" void kernel_launch(void* const* d_in, const int* in_sizes, int n_in,
                              void* d_out, int out_size, void* d_ws, size_t ws_size,
                              hipStream_t stream) {
  const float* x    = (const float*)d_in[0];
  const float* Wq   = (const float*)d_in[1];
  const float* Wk   = (const float*)d_in[2];
  const float* beta = (const float*)d_in[3];
  float* out = (float*)d_out;

  char* ws = (char*)d_ws;
  __bf16* xb  = (__bf16*)(ws);                         // 8 MB
  __bf16* Wkb = (__bf16*)(ws + (8ull  << 20));         // 2 MB
  __bf16* Wqb = (__bf16*)(ws + (10ull << 20));         // 2 MB
  __bf16* Wkt = (__bf16*)(ws + (12ull << 20));         // 2 MB
  __bf16* Wqt = (__bf16*)(ws + (14ull << 20));         // 2 MB
  __bf16* kp  = (__bf16*)(ws + (16ull << 20));         // 8 MB
  __bf16* qp  = (__bf16*)(ws + (24ull << 20));         // 8 MB
  __bf16* kpt = (__bf16*)(ws + (32ull << 20));         // 8 MB (l-permuted)
  __bf16* qpt = (__bf16*)(ws + (40ull << 20));         // 8 MB (l-permuted)
  __bf16* Gkp = (__bf16*)(ws + (48ull << 20));         // 8 MB
  __bf16* Gqp = (__bf16*)(ws + (56ull << 20));         // 8 MB
  float*  lse = (float*)(ws + (64ull << 20));          // 256 KB

  cvt_kernel<<<4096, 256, 0, stream>>>(x, xb, 1048576);
  cvt_kernel<<<1024, 256, 0, stream>>>(Wk, Wkb, 262144);
  cvt_kernel<<<1024, 256, 0, stream>>>(Wq, Wqb, 262144);
  wt_kernel<<<dim3(16, 16, 2), 256, 0, stream>>>(Wk, Wq, Wkt, Wqt);
  proj_kernel<<<dim3(16, 64, 2), 256, 0, stream>>>(xb, Wkb, Wqb, kp, qp, kpt, qpt);
  grad_kernel<0><<<512, 256, 0, stream>>>(kp, qp, qpt, beta, lse, Gkp);
  kscale_kernel<<<4096, 256, 0, stream>>>(kpt, lse);
  grad_kernel<1><<<512, 256, 0, stream>>>(qp, kp, kpt, beta, lse, Gqp);
  energy_kernel<<<2, 256, 0, stream>>>(lse, beta, out);
  gx_kernel<<<dim3(16, 64), 256, 0, stream>>>(Gkp, Gqp, Wkt, Wqt, out + 2);
}